// Round 1
// baseline (1827.056 us; speedup 1.0000x reference)
//
#include <hip/hip_runtime.h>
#include <hip/hip_bf16.h>
#include <stdint.h>

// Problem constants
#define NSLICE 4          // workgroups per direction in recurrence

typedef __attribute__((ext_vector_type(4))) float f32x4;
typedef __attribute__((ext_vector_type(8))) short bf16x8;

// ---- workspace layout (bytes) ----
#define WS_XBF   0u          // x gathered, bf16 [S=512][B=32][E=256]          = 8388608
#define WS_WIR   8388608u    // Wi permuted rows, bf16 [2048][256]             = 1048576
#define WS_BIAS  9437184u    // bi+bh permuted, f32 [2048]                     = 8192
#define WS_PRE   9445376u    // pre, bf16 [2][512 s][4 slice][512 tid][16]     = 67108864
#define WS_HALL  76554240u   // h states, bf16 [2][513 t][32 b][256 h]         = 16809984
#define WS_FLAGS 93364224u   // int [2][512]                                   = 4096
#define WS_EMIS  93368320u   // emissions f32 [32 b][512 s][16 t]              = 1048576
#define WS_CHK   94416896u   // CRF chunk mats f32 [32 b][32 c][16][16]        = 1048576
// total ~95.5 MB

__device__ __forceinline__ unsigned short f2bf(float x) {
    union { float f; unsigned int u; } v; v.f = x;
    return (unsigned short)((v.u + 0x7FFFu + ((v.u >> 16) & 1u)) >> 16);
}
__device__ __forceinline__ float bf2f(unsigned short b) {
    union { float f; unsigned int u; } v; v.u = ((unsigned int)b) << 16; return v.f;
}
__device__ __forceinline__ unsigned int pack2(float a, float b) {
    return (unsigned int)f2bf(a) | ((unsigned int)f2bf(b) << 16);
}
__device__ __forceinline__ float sigf(float x)  { return 1.0f / (1.0f + __expf(-x)); }
__device__ __forceinline__ float tanhf_(float x){ return 1.0f - 2.0f / (__expf(2.0f * x) + 1.0f); }

// ============ kernel 1: gather x -> bf16, permute Wi rows, combine biases, zero flags/h0 ============
__global__ __launch_bounds__(256) void k_prep(
    const int* __restrict__ tokens, const float* __restrict__ embed,
    const float* __restrict__ Wi_f, const float* __restrict__ Wi_b,
    const float* __restrict__ bi_f, const float* __restrict__ bh_f,
    const float* __restrict__ bi_b, const float* __restrict__ bh_b,
    char* __restrict__ ws)
{
    int blk = blockIdx.x, tid = threadIdx.x;
    unsigned short* xbf  = (unsigned short*)(ws + WS_XBF);
    unsigned short* wir  = (unsigned short*)(ws + WS_WIR);
    float* biasr         = (float*)(ws + WS_BIAS);
    if (blk < 2048) {                       // x gather: 8 rows/block
        int rr = tid >> 5, cc = tid & 31;
        int r = blk * 8 + rr;               // r = s*32+b
        int s = r >> 5, b = r & 31;
        int tok = tokens[b * 512 + s];
        int k = cc * 8;
        const float* src = embed + (size_t)tok * 256 + k;
        float4 a = *(const float4*)src;
        float4 c = *(const float4*)(src + 4);
        uint4 o; o.x = pack2(a.x, a.y); o.y = pack2(a.z, a.w);
        o.z = pack2(c.x, c.y); o.w = pack2(c.z, c.w);
        *(uint4*)(xbf + (size_t)r * 256 + k) = o;
    } else if (blk < 2304) {                // Wi row permute: dest row' = dir*1024 + j*256 + (g*64+hl)
        int rr = tid >> 5, cc = tid & 31;
        int rowp = (blk - 2048) * 8 + rr;   // 0..2047
        int dir = rowp >> 10, q = rowp & 1023;
        int j = q >> 8, rs = q & 255;
        int g = rs >> 6, hl = rs & 63;
        int srow = g * 256 + j * 64 + hl;
        const float* W = dir ? Wi_b : Wi_f;
        int k = cc * 8;
        const float* src = W + (size_t)srow * 256 + k;
        float4 a = *(const float4*)src;
        float4 c = *(const float4*)(src + 4);
        uint4 o; o.x = pack2(a.x, a.y); o.y = pack2(a.z, a.w);
        o.z = pack2(c.x, c.y); o.w = pack2(c.z, c.w);
        *(uint4*)(wir + (size_t)rowp * 256 + k) = o;
        if (cc == 0)
            biasr[rowp] = dir ? (bi_b[srow] + bh_b[srow]) : (bi_f[srow] + bh_f[srow]);
    } else {                                // zero flags + h0 for both dirs
        int g = (blk - 2304) * 256 + tid;   // 0..4095
        for (int u = g; u < 9216; u += 4096) {
            if (u < 1024) ((int*)(ws + WS_FLAGS))[u] = 0;
            else if (u < 5120) ((unsigned int*)(ws + WS_HALL))[u - 1024] = 0;
            else ((unsigned int*)(ws + WS_HALL + (size_t)513 * 16384))[u - 5120] = 0;
        }
    }
}

// ============ kernel 2: pre = x*Wi^T + bias, written in recurrence-lane-private layout ============
__global__ __launch_bounds__(256) void k_pregemm(char* __restrict__ ws)
{
    __shared__ unsigned short Asb[128 * 136];
    __shared__ unsigned short Bsb[64 * 136];
    const unsigned short* xbf = (const unsigned short*)(ws + WS_XBF);
    const unsigned short* wir = (const unsigned short*)(ws + WS_WIR);
    const float* biasr        = (const float*)(ws + WS_BIAS);
    unsigned short* pre       = (unsigned short*)(ws + WS_PRE);
    int blk = blockIdx.x, tid = threadIdx.x;
    int mb = blk >> 5, nb = blk & 31;
    int Mbase = mb * 128, Nbase = nb * 64;
    int w = tid >> 6, l = tid & 63, col = l & 15, quad = l >> 4;
    f32x4 acc[4][2];
    #pragma unroll
    for (int a = 0; a < 4; ++a)
        #pragma unroll
        for (int b = 0; b < 2; ++b) acc[a][b] = (f32x4){0.f, 0.f, 0.f, 0.f};

    for (int kh = 0; kh < 2; ++kh) {
        __syncthreads();
        #pragma unroll
        for (int i = 0; i < 8; ++i) {       // A half-tile 128x128 bf16
            int c = tid + i * 256;
            int row = c >> 4, c16 = c & 15;
            uint4 v = *(const uint4*)(xbf + ((size_t)(Mbase + row) * 256 + kh * 128 + c16 * 8));
            *(uint4*)(Asb + row * 136 + c16 * 8) = v;
        }
        #pragma unroll
        for (int i = 0; i < 4; ++i) {       // B half-tile 64x128 bf16
            int c = tid + i * 256;
            int row = c >> 4, c16 = c & 15;
            uint4 v = *(const uint4*)(wir + ((size_t)(Nbase + row) * 256 + kh * 128 + c16 * 8));
            *(uint4*)(Bsb + row * 136 + c16 * 8) = v;
        }
        __syncthreads();
        int mhalf = w >> 1, nh = w & 1;
        #pragma unroll
        for (int kt = 0; kt < 4; ++kt) {
            bf16x8 bfr[2];
            #pragma unroll
            for (int nn = 0; nn < 2; ++nn)
                bfr[nn] = *(const bf16x8*)(Bsb + (16 * (nh * 2 + nn) + col) * 136 + kt * 32 + quad * 8);
            #pragma unroll
            for (int mm = 0; mm < 4; ++mm) {
                bf16x8 afr = *(const bf16x8*)(Asb + (16 * (mhalf * 4 + mm) + col) * 136 + kt * 32 + quad * 8);
                #pragma unroll
                for (int nn = 0; nn < 2; ++nn)
                    acc[mm][nn] = __builtin_amdgcn_mfma_f32_16x16x32_bf16(afr, bfr[nn], acc[mm][nn], 0, 0, 0);
            }
        }
    }
    // epilogue: + bias, bf16, permuted store matching recurrence lane layout
    #pragma unroll
    for (int mm = 0; mm < 4; ++mm) {
        int m_t = (w >> 1) * 4 + mm;
        int s = (Mbase >> 5) + (m_t >> 1);
        int bhalf = m_t & 1;
        #pragma unroll
        for (int nn = 0; nn < 2; ++nn) {
            int ncol = Nbase + 16 * ((w & 1) * 2 + nn) + col;
            int dir = ncol >> 10, j = (ncol >> 8) & 3, r = ncol & 255;
            int g = r >> 6, hl16 = (r >> 4) & 3;
            int tidp = (bhalf * 4 + hl16) * 64 + l;
            float bv = biasr[ncol];
            f32x4 a = acc[mm][nn];
            uint2 o;
            o.x = pack2(a[0] + bv, a[1] + bv);
            o.y = pack2(a[2] + bv, a[3] + bv);
            size_t off = (((size_t)(dir * 512 + s) * 4 + j) * 512 + tidp) * 16 + g * 4;
            *(uint2*)(pre + off) = o;
        }
    }
}

// ============ kernel 3: persistent bidirectional LSTM recurrence ============
// grid = 8: blk>>2 = dir, blk&3 = hidden-slice j (64 units). 512 threads = 8 waves.
// wave w: m = w>>2 (b-half), hl16 = w&3 (16-unit hidden group). Wh fragments persistent in VGPRs.
__global__ __launch_bounds__(512, 2) void k_rec(
    const float* __restrict__ Wh_f, const float* __restrict__ Wh_b, char* __restrict__ ws)
{
    __shared__ unsigned short hbuf[32 * 264];
    __shared__ unsigned short hst[8 * 16 * 20];
    int blk = blockIdx.x, tid = threadIdx.x;
    int dir = blk >> 2, j = blk & 3;
    int w = tid >> 6, l = tid & 63, col = l & 15, quad = l >> 4;
    int m = w >> 2, hl16 = w & 3;
    const float* Wh = dir ? Wh_b : Wh_f;
    const unsigned short* pre = (const unsigned short*)(ws + WS_PRE);
    unsigned short* hall      = (unsigned short*)(ws + WS_HALL);
    int* flags                = (int*)(ws + WS_FLAGS);

    // persistent weight B-fragments: wf[gate][kt], rows g*256 + j*64 + hl16*16 + col
    bf16x8 wf[4][8];
    #pragma unroll
    for (int g = 0; g < 4; ++g) {
        int grow = g * 256 + j * 64 + hl16 * 16 + col;
        #pragma unroll
        for (int kt = 0; kt < 8; ++kt) {
            const float* src = Wh + (size_t)grow * 256 + kt * 32 + quad * 8;
            float4 x0 = *(const float4*)src;
            float4 x1 = *(const float4*)(src + 4);
            bf16x8 f;
            f[0] = (short)f2bf(x0.x); f[1] = (short)f2bf(x0.y);
            f[2] = (short)f2bf(x0.z); f[3] = (short)f2bf(x0.w);
            f[4] = (short)f2bf(x1.x); f[5] = (short)f2bf(x1.y);
            f[6] = (short)f2bf(x1.z); f[7] = (short)f2bf(x1.w);
            wf[g][kt] = f;
        }
    }
    float cst[4] = {0.f, 0.f, 0.f, 0.f};
    size_t hbase_u = (size_t)dir * 513 * 8192;   // ushort units

    for (int st = 0; st < 512; ++st) {
        int s = dir ? (511 - st) : st;
        // pre values for this lane (independent of h -> issue before spin)
        const uint4* pp = (const uint4*)(pre + ((((size_t)(dir * 512 + s)) * 4 + j) * 512 + tid) * 16);
        uint4 p0 = pp[0], p1 = pp[1];
        if (st > 0 && tid == 0) {
            while (__hip_atomic_load(flags + (dir * 512 + st - 1),
                                     __ATOMIC_ACQUIRE, __HIP_MEMORY_SCOPE_AGENT) < NSLICE) {}
        }
        __syncthreads();
        { // stage h(st) 16KB -> LDS (padded rows)
            const uint4* hsrc = (const uint4*)(hall + hbase_u + (size_t)st * 8192);
            #pragma unroll
            for (int i = 0; i < 2; ++i) {
                int c = tid + i * 512;
                int row = c >> 5, c16 = c & 31;
                uint4 v = hsrc[row * 32 + c16];
                *(uint4*)(hbuf + row * 264 + c16 * 8) = v;
            }
        }
        __syncthreads();
        f32x4 acc[4];
        #pragma unroll
        for (int g = 0; g < 4; ++g) acc[g] = (f32x4){0.f, 0.f, 0.f, 0.f};
        #pragma unroll
        for (int kt = 0; kt < 8; ++kt) {
            bf16x8 af = *(const bf16x8*)(hbuf + (m * 16 + col) * 264 + kt * 32 + quad * 8);
            #pragma unroll
            for (int g = 0; g < 4; ++g)
                acc[g] = __builtin_amdgcn_mfma_f32_16x16x32_bf16(af, wf[g][kt], acc[g], 0, 0, 0);
        }
        unsigned int pw[8] = {p0.x, p0.y, p0.z, p0.w, p1.x, p1.y, p1.z, p1.w};
        float z[4][4];
        #pragma unroll
        for (int g = 0; g < 4; ++g) {
            #pragma unroll
            for (int r2 = 0; r2 < 2; ++r2) {
                unsigned int u = pw[g * 2 + r2];
                z[g][r2 * 2]     = acc[g][r2 * 2]     + bf2f((unsigned short)(u & 0xffff));
                z[g][r2 * 2 + 1] = acc[g][r2 * 2 + 1] + bf2f((unsigned short)(u >> 16));
            }
        }
        unsigned short hb16[4];
        #pragma unroll
        for (int r = 0; r < 4; ++r) {   // gates i,f,g,o
            float ci = sigf(z[1][r]) * cst[r] + sigf(z[0][r]) * tanhf_(z[2][r]);
            cst[r] = ci;
            hb16[r] = f2bf(sigf(z[3][r]) * tanhf_(ci));
        }
        // transpose-stage this wave's 16x16 h tile through LDS, then coalesced-ish global store
        unsigned short* hw = hst + w * 320;
        #pragma unroll
        for (int r = 0; r < 4; ++r) hw[(quad * 4 + r) * 20 + col] = hb16[r];
        int rrow = l >> 2, cpart = l & 3;
        uint2 hv = *(const uint2*)(hw + rrow * 20 + cpart * 4);
        size_t dsto = hbase_u + (size_t)(st + 1) * 8192 + (size_t)(m * 16 + rrow) * 256
                    + j * 64 + hl16 * 16 + cpart * 4;
        *(uint2*)(hall + dsto) = hv;
        __syncthreads();   // drains vmem stores before signaling
        if (tid == 0)
            __hip_atomic_fetch_add(flags + (dir * 512 + st), 1,
                                   __ATOMIC_RELEASE, __HIP_MEMORY_SCOPE_AGENT);
    }
}

// ============ kernel 4: emissions e[b][s][t] = [hf|hb] . Wt[t] + bt ============
__global__ __launch_bounds__(256) void k_emis(
    const float* __restrict__ Wt, const float* __restrict__ bt, char* __restrict__ ws)
{
    __shared__ float WtL[16 * 528];
    __shared__ unsigned short hrow[16 * 536];
    __shared__ float btL[16];
    int blk = blockIdx.x, tid = threadIdx.x;
    int sbb = blk * 16;
    int s = sbb >> 5, bbase = sbb & 31;     // 16 batch rows per block, fixed s
    const unsigned short* hall = (const unsigned short*)(ws + WS_HALL);
    float* emis = (float*)(ws + WS_EMIS);
    #pragma unroll
    for (int i = 0; i < 8; ++i) {           // Wt 16x512 f32 -> LDS
        int c = tid + i * 256;
        int trow = c >> 7, c128 = c & 127;
        float4 v = *(const float4*)(Wt + (size_t)trow * 512 + c128 * 4);
        *(float4*)(WtL + trow * 528 + c128 * 4) = v;
    }
    #pragma unroll
    for (int i = 0; i < 4; ++i) {           // h rows: [i][0..255]=hf(s), [i][256..511]=hb(s)
        int c = tid + i * 256;
        int row = c >> 6, c6 = c & 63, half = c6 >> 5, c16 = c6 & 31;
        size_t base = half == 0 ? (size_t)(s + 1) * 8192 : ((size_t)513 + (512 - s)) * 8192;
        uint4 v = *(const uint4*)(hall + base + (size_t)(bbase + row) * 256 + c16 * 8);
        *(uint4*)(hrow + row * 536 + half * 256 + c16 * 8) = v;
    }
    if (tid < 16) btL[tid] = bt[tid];
    __syncthreads();
    int t = tid >> 4, i = tid & 15;
    float acc = btL[t];
    const float* wrow = WtL + t * 528;
    const unsigned short* hr = hrow + i * 536;
    #pragma unroll 8
    for (int k = 0; k < 512; k += 4) {
        uint2 hu = *(const uint2*)(hr + k);
        float4 wv = *(const float4*)(wrow + k);
        acc += bf2f((unsigned short)(hu.x & 0xffff)) * wv.x
             + bf2f((unsigned short)(hu.x >> 16))    * wv.y
             + bf2f((unsigned short)(hu.y & 0xffff)) * wv.z
             + bf2f((unsigned short)(hu.y >> 16))    * wv.w;
    }
    emis[((size_t)(bbase + i) * 512 + s) * 16 + t] = acc;
}

// ============ kernel 5: CRF chunk products (log-semiring, associative) ============
// block = (b, chunk c of 16 steps): P_c = M_{16c+15} (x) ... (x) M_{16c},  M_s[t,p]=trans[t,p]+e[s,t]
__global__ __launch_bounds__(256) void k_crfc(const float* __restrict__ trans, char* __restrict__ ws)
{
    __shared__ float trL[16 * 17];
    __shared__ float est[16 * 16];
    __shared__ float Pb[2][16 * 17];
    int blk = blockIdx.x, tid = threadIdx.x;
    int b = blk >> 5, c = blk & 31;
    int t = tid >> 4, p = tid & 15;
    const float* emis = (const float*)(ws + WS_EMIS);
    float* chk = (float*)(ws + WS_CHK);
    trL[t * 17 + p] = trans[t * 16 + p];
    est[t * 16 + p] = emis[((size_t)b * 512 + c * 16 + t) * 16 + p];  // est[si][tt]: si=t var, tt=p var
    __syncthreads();
    float tr[16];
    #pragma unroll
    for (int q = 0; q < 16; ++q) tr[q] = trL[t * 17 + q];
    float out = trL[t * 17 + p] + est[0 * 16 + t];
    Pb[0][t * 17 + p] = out;
    __syncthreads();
    int cur = 0;
    for (int si = 1; si < 16; ++si) {
        float v[16]; float mx = -3.0e38f;
        #pragma unroll
        for (int q = 0; q < 16; ++q) { v[q] = tr[q] + Pb[cur][q * 17 + p]; mx = fmaxf(mx, v[q]); }
        float ss = 0.f;
        #pragma unroll
        for (int q = 0; q < 16; ++q) ss += __expf(v[q] - mx);
        out = est[si * 16 + t] + mx + __logf(ss);
        Pb[1 - cur][t * 17 + p] = out;
        __syncthreads();
        cur = 1 - cur;
    }
    chk[(size_t)(b * 32 + c) * 256 + t * 16 + p] = out;
}

// ============ kernel 6: fold 32 chunk matrices per batch, apply alpha0/stop, emit log_Z ============
__global__ __launch_bounds__(256) void k_crff(
    const float* __restrict__ trans, char* __restrict__ ws, float* __restrict__ out)
{
    __shared__ float Cst[16 * 17];
    __shared__ float Pb[2][16 * 17];
    __shared__ float af[16];
    int b = blockIdx.x, tid = threadIdx.x;
    int t = tid >> 4, p = tid & 15;
    const float* chk = (const float*)(ws + WS_CHK);
    Pb[0][t * 17 + p] = chk[(size_t)(b * 32) * 256 + t * 16 + p];
    __syncthreads();
    int cur = 0;
    for (int ci = 1; ci < 32; ++ci) {
        Cst[t * 17 + p] = chk[(size_t)(b * 32 + ci) * 256 + t * 16 + p];
        __syncthreads();
        float v[16]; float mx = -3.0e38f;
        #pragma unroll
        for (int q = 0; q < 16; ++q) { v[q] = Cst[t * 17 + q] + Pb[cur][q * 17 + p]; mx = fmaxf(mx, v[q]); }
        float ss = 0.f;
        #pragma unroll
        for (int q = 0; q < 16; ++q) ss += __expf(v[q] - mx);
        float outv = mx + __logf(ss);
        Pb[1 - cur][t * 17 + p] = outv;
        __syncthreads();
        cur = 1 - cur;
    }
    float vfin = Pb[cur][t * 17 + p] + ((p == 14) ? 0.0f : -10000.0f);  // alpha0: START=14
    Cst[t * 17 + p] = vfin;
    __syncthreads();
    if (tid < 16) {
        float mx = -3.0e38f;
        for (int q = 0; q < 16; ++q) mx = fmaxf(mx, Cst[tid * 17 + q]);
        float ss = 0.f;
        for (int q = 0; q < 16; ++q) ss += __expf(Cst[tid * 17 + q] - mx);
        af[tid] = mx + __logf(ss) + trans[15 * 16 + tid];               // STOP=15
    }
    __syncthreads();
    if (tid == 0) {
        float mx = -3.0e38f;
        for (int q = 0; q < 16; ++q) mx = fmaxf(mx, af[q]);
        float ss = 0.f;
        for (int q = 0; q < 16; ++q) ss += __expf(af[q] - mx);
        out[b] = mx + __logf(ss);
    }
}

extern "C" void kernel_launch(void* const* d_in, const int* in_sizes, int n_in,
                              void* d_out, int out_size, void* d_ws, size_t ws_size,
                              hipStream_t stream)
{
    const int*   tokens = (const int*)d_in[0];
    const float* embed  = (const float*)d_in[1];
    const float* Wi_f   = (const float*)d_in[2];
    const float* Wh_f   = (const float*)d_in[3];
    const float* bi_f   = (const float*)d_in[4];
    const float* bh_f   = (const float*)d_in[5];
    const float* Wi_b   = (const float*)d_in[6];
    const float* Wh_b   = (const float*)d_in[7];
    const float* bi_b   = (const float*)d_in[8];
    const float* bh_b   = (const float*)d_in[9];
    const float* Wt     = (const float*)d_in[10];
    const float* bt     = (const float*)d_in[11];
    const float* trans  = (const float*)d_in[12];
    char* ws = (char*)d_ws;
    float* out = (float*)d_out;

    hipLaunchKernelGGL(k_prep, dim3(2320), dim3(256), 0, stream,
                       tokens, embed, Wi_f, Wi_b, bi_f, bh_f, bi_b, bh_b, ws);
    hipLaunchKernelGGL(k_pregemm, dim3(4096), dim3(256), 0, stream, ws);
    hipLaunchKernelGGL(k_rec, dim3(8), dim3(512), 0, stream, Wh_f, Wh_b, ws);
    hipLaunchKernelGGL(k_emis, dim3(1024), dim3(256), 0, stream, Wt, bt, ws);
    hipLaunchKernelGGL(k_crfc, dim3(1024), dim3(256), 0, stream, trans, ws);
    hipLaunchKernelGGL(k_crff, dim3(32), dim3(256), 0, stream, trans, ws, out);
}

// Round 5
// 1610.869 us; speedup vs baseline: 1.1342x; 1.1342x over previous
//
#include <hip/hip_runtime.h>
#include <hip/hip_bf16.h>
#include <stdint.h>

typedef __attribute__((ext_vector_type(4))) float f32x4;
typedef __attribute__((ext_vector_type(8))) short bf16x8;

#define SENT 0xFFFFFFFFFFFFFFFFULL   // 4x bf16 NaN — real h (sigmoid*tanh) is always finite

// ---- workspace layout (bytes) ----
#define WS_XBF   0u          // x gathered, bf16 [S=512][B=32][E=256]          = 8388608
#define WS_WIR   8388608u    // Wi permuted rows, bf16 [2048][256]             = 1048576
#define WS_BIAS  9437184u    // bi+bh permuted, f32 [2048]                     = 8192
#define WS_PRE   9445376u    // pre, bf16 [2][512 s][4 slice][512 tid][16]     = 67108864
#define WS_HALL  76554240u   // h states, bf16 [2][513 t][32 b][256 h]        = 16809984
#define WS_EMIS  93368320u   // emissions f32 [32 b][512 s][16 t]              = 1048576
#define WS_CHK   94416896u   // CRF chunk mats f32 [32 b][32 c][16][16]        = 1048576

__device__ __forceinline__ unsigned short f2bf(float x) {
    union { float f; unsigned int u; } v; v.f = x;
    return (unsigned short)((v.u + 0x7FFFu + ((v.u >> 16) & 1u)) >> 16);
}
__device__ __forceinline__ float bf2f(unsigned short b) {
    union { float f; unsigned int u; } v; v.u = ((unsigned int)b) << 16; return v.f;
}
__device__ __forceinline__ unsigned int pack2(float a, float b) {
    return (unsigned int)f2bf(a) | ((unsigned int)f2bf(b) << 16);
}
__device__ __forceinline__ float sigf(float x)  { return 1.0f / (1.0f + __expf(-x)); }
__device__ __forceinline__ float tanhf_(float x){ return 1.0f - 2.0f / (__expf(2.0f * x) + 1.0f); }

// ============ kernel 1: gather x -> bf16, permute Wi rows, combine biases, sentinel-fill h ============
__global__ __launch_bounds__(256) void k_prep(
    const int* __restrict__ tokens, const float* __restrict__ embed,
    const float* __restrict__ Wi_f, const float* __restrict__ Wi_b,
    const float* __restrict__ bi_f, const float* __restrict__ bh_f,
    const float* __restrict__ bi_b, const float* __restrict__ bh_b,
    char* __restrict__ ws)
{
    int blk = blockIdx.x, tid = threadIdx.x;
    unsigned short* xbf  = (unsigned short*)(ws + WS_XBF);
    unsigned short* wir  = (unsigned short*)(ws + WS_WIR);
    float* biasr         = (float*)(ws + WS_BIAS);
    if (blk < 2048) {                       // x gather: 8 rows/block
        int rr = tid >> 5, cc = tid & 31;
        int r = blk * 8 + rr;               // r = s*32+b
        int s = r >> 5, b = r & 31;
        int tok = tokens[b * 512 + s];
        int k = cc * 8;
        const float* src = embed + (size_t)tok * 256 + k;
        float4 a = *(const float4*)src;
        float4 c = *(const float4*)(src + 4);
        uint4 o; o.x = pack2(a.x, a.y); o.y = pack2(a.z, a.w);
        o.z = pack2(c.x, c.y); o.w = pack2(c.z, c.w);
        *(uint4*)(xbf + (size_t)r * 256 + k) = o;
    } else if (blk < 2304) {                // Wi row permute: dest row' = dir*1024 + j*256 + (g*64+hl)
        int rr = tid >> 5, cc = tid & 31;
        int rowp = (blk - 2048) * 8 + rr;   // 0..2047
        int dir = rowp >> 10, q = rowp & 1023;
        int j = q >> 8, rs = q & 255;
        int g = rs >> 6, hl = rs & 63;
        int srow = g * 256 + j * 64 + hl;
        const float* W = dir ? Wi_b : Wi_f;
        int k = cc * 8;
        const float* src = W + (size_t)srow * 256 + k;
        float4 a = *(const float4*)src;
        float4 c = *(const float4*)(src + 4);
        uint4 o; o.x = pack2(a.x, a.y); o.y = pack2(a.z, a.w);
        o.z = pack2(c.x, c.y); o.w = pack2(c.z, c.w);
        *(uint4*)(wir + (size_t)rowp * 256 + k) = o;
        if (cc == 0)
            biasr[rowp] = dir ? (bi_b[srow] + bh_b[srow]) : (bi_f[srow] + bh_f[srow]);
    } else {                                // h buffers: slot 0 -> 0.0, slots 1..512 -> sentinel
        size_t g = (size_t)(blk - 2304) * 256 + tid;
        uint4* hall4 = (uint4*)(ws + WS_HALL);
        const unsigned int NF = 0xFFFFFFFFu;
        for (size_t u = g; u < 1050624u; u += 65536u) {   // 16,809,984 B / 16
            size_t slot = (u >> 10) % 513u;                // 1024 uint4 per 16KB t-slot (r4 fix)
            uint4 val;
            if (slot == 0) { val.x = 0u; val.y = 0u; val.z = 0u; val.w = 0u; }
            else           { val.x = NF; val.y = NF; val.z = NF; val.w = NF; }
            hall4[u] = val;
        }
    }
}

// ============ kernel 2: pre = x*Wi^T + bias, written in recurrence-lane-private layout ============
__global__ __launch_bounds__(256) void k_pregemm(char* __restrict__ ws)
{
    __shared__ unsigned short Asb[128 * 136];
    __shared__ unsigned short Bsb[64 * 136];
    const unsigned short* xbf = (const unsigned short*)(ws + WS_XBF);
    const unsigned short* wir = (const unsigned short*)(ws + WS_WIR);
    const float* biasr        = (const float*)(ws + WS_BIAS);
    unsigned short* pre       = (unsigned short*)(ws + WS_PRE);
    int blk = blockIdx.x, tid = threadIdx.x;
    int mb = blk >> 5, nb = blk & 31;
    int Mbase = mb * 128, Nbase = nb * 64;
    int w = tid >> 6, l = tid & 63, col = l & 15, quad = l >> 4;
    f32x4 acc[4][2];
    #pragma unroll
    for (int a = 0; a < 4; ++a)
        #pragma unroll
        for (int b = 0; b < 2; ++b) acc[a][b] = (f32x4){0.f, 0.f, 0.f, 0.f};

    for (int kh = 0; kh < 2; ++kh) {
        __syncthreads();
        #pragma unroll
        for (int i = 0; i < 8; ++i) {       // A half-tile 128x128 bf16
            int c = tid + i * 256;
            int row = c >> 4, c16 = c & 15;
            uint4 v = *(const uint4*)(xbf + ((size_t)(Mbase + row) * 256 + kh * 128 + c16 * 8));
            *(uint4*)(Asb + row * 136 + c16 * 8) = v;
        }
        #pragma unroll
        for (int i = 0; i < 4; ++i) {       // B half-tile 64x128 bf16
            int c = tid + i * 256;
            int row = c >> 4, c16 = c & 15;
            uint4 v = *(const uint4*)(wir + ((size_t)(Nbase + row) * 256 + kh * 128 + c16 * 8));
            *(uint4*)(Bsb + row * 136 + c16 * 8) = v;
        }
        __syncthreads();
        int mhalf = w >> 1, nh = w & 1;
        #pragma unroll
        for (int kt = 0; kt < 4; ++kt) {
            bf16x8 bfr[2];
            #pragma unroll
            for (int nn = 0; nn < 2; ++nn)
                bfr[nn] = *(const bf16x8*)(Bsb + (16 * (nh * 2 + nn) + col) * 136 + kt * 32 + quad * 8);
            #pragma unroll
            for (int mm = 0; mm < 4; ++mm) {
                bf16x8 afr = *(const bf16x8*)(Asb + (16 * (mhalf * 4 + mm) + col) * 136 + kt * 32 + quad * 8);
                #pragma unroll
                for (int nn = 0; nn < 2; ++nn)
                    acc[mm][nn] = __builtin_amdgcn_mfma_f32_16x16x32_bf16(afr, bfr[nn], acc[mm][nn], 0, 0, 0);
            }
        }
    }
    // epilogue: + bias, bf16, permuted store matching recurrence lane layout
    #pragma unroll
    for (int mm = 0; mm < 4; ++mm) {
        int m_t = (w >> 1) * 4 + mm;
        int s = (Mbase >> 5) + (m_t >> 1);
        int bhalf = m_t & 1;
        #pragma unroll
        for (int nn = 0; nn < 2; ++nn) {
            int ncol = Nbase + 16 * ((w & 1) * 2 + nn) + col;
            int dir = ncol >> 10, j = (ncol >> 8) & 3, r = ncol & 255;
            int g = r >> 6, hl16 = (r >> 4) & 3;
            int tidp = (bhalf * 4 + hl16) * 64 + l;
            float bv = biasr[ncol];
            f32x4 a = acc[mm][nn];
            uint2 o;
            o.x = pack2(a[0] + bv, a[1] + bv);
            o.y = pack2(a[2] + bv, a[3] + bv);
            size_t off = (((size_t)(dir * 512 + s) * 4 + j) * 512 + tidp) * 16 + g * 4;
            *(uint2*)(pre + off) = o;
        }
    }
}

// ============ kernel 3: persistent bidirectional LSTM recurrence ============
// grid = 8: blk>>2 = dir, blk&3 = hidden-slice j (64 units). 512 threads = 8 waves.
// Sync design: relaxed sc1 LOADS can be served stale (r3 evidence); only ATOMICS are
// reliably coherent cross-XCD. ALL cross-block h traffic is atomic:
//  - producer: global_atomic_swap_x2 (executes at IC); no flag, no fence
//  - consumer: polls the DATA with fetch_add(0) u64 until != sentinel (bf16-NaN pattern,
//    unreachable for real h). Per-address atomic-vs-atomic coherence.
//  - own slice (1/4) comes from LDS hst, no global round-trip.
__global__ __launch_bounds__(512, 2) void k_rec(
    const float* __restrict__ Wh_f, const float* __restrict__ Wh_b, char* __restrict__ ws)
{
    __shared__ unsigned short hbuf[32 * 264];
    __shared__ unsigned short hst[8 * 16 * 20];
    int blk = blockIdx.x, tid = threadIdx.x;
    int dir = blk >> 2, j = blk & 3;
    int w = tid >> 6, l = tid & 63, col = l & 15, quad = l >> 4;
    int m = w >> 2, hl16 = w & 3;
    const float* Wh = dir ? Wh_b : Wh_f;
    const unsigned short* pre = (const unsigned short*)(ws + WS_PRE);
    unsigned short* hall      = (unsigned short*)(ws + WS_HALL);

    // persistent weight B-fragments: wf[gate][kt], rows g*256 + j*64 + hl16*16 + col
    bf16x8 wf[4][8];
    #pragma unroll
    for (int g = 0; g < 4; ++g) {
        int grow = g * 256 + j * 64 + hl16 * 16 + col;
        #pragma unroll
        for (int kt = 0; kt < 8; ++kt) {
            const float* src = Wh + (size_t)grow * 256 + kt * 32 + quad * 8;
            float4 x0 = *(const float4*)src;
            float4 x1 = *(const float4*)(src + 4);
            bf16x8 f;
            f[0] = (short)f2bf(x0.x); f[1] = (short)f2bf(x0.y);
            f[2] = (short)f2bf(x0.z); f[3] = (short)f2bf(x0.w);
            f[4] = (short)f2bf(x1.x); f[5] = (short)f2bf(x1.y);
            f[6] = (short)f2bf(x1.z); f[7] = (short)f2bf(x1.w);
            wf[g][kt] = f;
        }
    }
    // zero hst: own-slice source for st=0 (h0 = 0)
    for (int u = tid; u < 1280; u += 512) ((unsigned int*)hst)[u] = 0;
    __syncthreads();

    float cst[4] = {0.f, 0.f, 0.f, 0.f};
    size_t hbase_u = (size_t)dir * 513 * 8192;   // ushort units

    for (int st = 0; st < 512; ++st) {
        int s = dir ? (511 - st) : st;
        // pre values for this lane (independent of h -> issued early, latency hidden)
        const uint4* pp = (const uint4*)(pre + ((((size_t)(dir * 512 + s)) * 4 + j) * 512 + tid) * 16);
        uint4 p0 = pp[0], p1 = pp[1];

        // ---- stage h(st) -> hbuf: 2048 chunks of 8B; 4 per lane ----
        unsigned short* hsl = hall + hbase_u + (size_t)st * 8192;
        unsigned long long v[4];
        int rows[4], c8s[4];
        bool own[4];
        #pragma unroll
        for (int i = 0; i < 4; ++i) {
            int q = tid + i * 512;
            int row = q >> 6, c8 = q & 63;          // 64x 8B chunks per 512B row
            rows[i] = row; c8s[i] = c8;
            own[i] = (c8 >= j * 16) && (c8 < j * 16 + 16);
            if (!own[i])                              // first issue: all remote chunks in flight
                v[i] = __hip_atomic_fetch_add((unsigned long long*)(hsl + (size_t)q * 4), 0ULL,
                                              __ATOMIC_RELAXED, __HIP_MEMORY_SCOPE_AGENT);
        }
        #pragma unroll
        for (int i = 0; i < 4; ++i) {
            if (own[i]) {                             // own slice: from LDS hst (h(st))
                int lc = c8s[i] * 4 - j * 64;         // ushort offset within slice, 0..63
                int hl = lc >> 4, c4 = lc & 15;
                int wp = (rows[i] >> 4) * 4 + hl, r_in = rows[i] & 15;
                v[i] = *(const unsigned long long*)(hst + wp * 320 + r_in * 20 + c4);
            } else {
                while (v[i] == SENT)
                    v[i] = __hip_atomic_fetch_add((unsigned long long*)(hsl + (size_t)(tid + i * 512) * 4),
                                                  0ULL, __ATOMIC_RELAXED, __HIP_MEMORY_SCOPE_AGENT);
            }
        }
        #pragma unroll
        for (int i = 0; i < 4; ++i)
            *(unsigned long long*)(hbuf + rows[i] * 264 + c8s[i] * 4) = v[i];
        __syncthreads();

        // ---- MFMA: z = h(st) @ Wh_slice^T ----
        f32x4 acc[4];
        #pragma unroll
        for (int g = 0; g < 4; ++g) acc[g] = (f32x4){0.f, 0.f, 0.f, 0.f};
        #pragma unroll
        for (int kt = 0; kt < 8; ++kt) {
            bf16x8 af = *(const bf16x8*)(hbuf + (m * 16 + col) * 264 + kt * 32 + quad * 8);
            #pragma unroll
            for (int g = 0; g < 4; ++g)
                acc[g] = __builtin_amdgcn_mfma_f32_16x16x32_bf16(af, wf[g][kt], acc[g], 0, 0, 0);
        }
        unsigned int pw[8] = {p0.x, p0.y, p0.z, p0.w, p1.x, p1.y, p1.z, p1.w};
        float z[4][4];
        #pragma unroll
        for (int g = 0; g < 4; ++g) {
            #pragma unroll
            for (int r2 = 0; r2 < 2; ++r2) {
                unsigned int u = pw[g * 2 + r2];
                z[g][r2 * 2]     = acc[g][r2 * 2]     + bf2f((unsigned short)(u & 0xffff));
                z[g][r2 * 2 + 1] = acc[g][r2 * 2 + 1] + bf2f((unsigned short)(u >> 16));
            }
        }
        unsigned short hb16[4];
        #pragma unroll
        for (int r = 0; r < 4; ++r) {   // gates i,f,g,o
            float ci = sigf(z[1][r]) * cst[r] + sigf(z[0][r]) * tanhf_(z[2][r]);
            cst[r] = ci;
            hb16[r] = f2bf(sigf(z[3][r]) * tanhf_(ci));
        }
        // transpose-stage this wave's 16x16 h tile into hst (also = own-slice source next step)
        unsigned short* hw = hst + w * 320;
        #pragma unroll
        for (int r = 0; r < 4; ++r) hw[(quad * 4 + r) * 20 + col] = hb16[r];
        int rrow = l >> 2, cpart = l & 3;
        unsigned long long hv = *(const unsigned long long*)(hw + rrow * 20 + cpart * 4);
        size_t dsto = hbase_u + (size_t)(st + 1) * 8192 + (size_t)(m * 16 + rrow) * 256
                    + j * 64 + hl16 * 16 + cpart * 4;
        // atomic swap: executes AT the IC -> consumers' atomic polls see it; no fence needed
        (void)__hip_atomic_exchange((unsigned long long*)(hall + dsto), hv,
                                    __ATOMIC_RELAXED, __HIP_MEMORY_SCOPE_AGENT);
        __syncthreads();   // hst/hbuf reuse safety for next iteration
    }
}

// ============ kernel 4: emissions e[b][s][t] = [hf|hb] . Wt[t] + bt ============
__global__ __launch_bounds__(256) void k_emis(
    const float* __restrict__ Wt, const float* __restrict__ bt, char* __restrict__ ws)
{
    __shared__ float WtL[16 * 528];
    __shared__ unsigned short hrow[16 * 536];
    __shared__ float btL[16];
    int blk = blockIdx.x, tid = threadIdx.x;
    int sbb = blk * 16;
    int s = sbb >> 5, bbase = sbb & 31;     // 16 batch rows per block, fixed s
    const unsigned short* hall = (const unsigned short*)(ws + WS_HALL);
    float* emis = (float*)(ws + WS_EMIS);
    #pragma unroll
    for (int i = 0; i < 8; ++i) {           // Wt 16x512 f32 -> LDS
        int c = tid + i * 256;
        int trow = c >> 7, c128 = c & 127;
        float4 v = *(const float4*)(Wt + (size_t)trow * 512 + c128 * 4);
        *(float4*)(WtL + trow * 528 + c128 * 4) = v;
    }
    #pragma unroll
    for (int i = 0; i < 4; ++i) {           // h rows: [i][0..255]=hf(s), [i][256..511]=hb(s)
        int c = tid + i * 256;
        int row = c >> 6, c6 = c & 63, half = c6 >> 5, c16 = c6 & 31;
        size_t base = half == 0 ? (size_t)(s + 1) * 8192 : ((size_t)513 + (512 - s)) * 8192;
        uint4 v = *(const uint4*)(hall + base + (size_t)(bbase + row) * 256 + c16 * 8);
        *(uint4*)(hrow + row * 536 + half * 256 + c16 * 8) = v;
    }
    if (tid < 16) btL[tid] = bt[tid];
    __syncthreads();
    int t = tid >> 4, i = tid & 15;
    float acc = btL[t];
    const float* wrow = WtL + t * 528;
    const unsigned short* hr = hrow + i * 536;
    #pragma unroll 8
    for (int k = 0; k < 512; k += 4) {
        uint2 hu = *(const uint2*)(hr + k);
        float4 wv = *(const float4*)(wrow + k);
        acc += bf2f((unsigned short)(hu.x & 0xffff)) * wv.x
             + bf2f((unsigned short)(hu.x >> 16))    * wv.y
             + bf2f((unsigned short)(hu.y & 0xffff)) * wv.z
             + bf2f((unsigned short)(hu.y >> 16))    * wv.w;
    }
    emis[((size_t)(bbase + i) * 512 + s) * 16 + t] = acc;
}

// ============ kernel 5: CRF chunk products (log-semiring, associative) ============
__global__ __launch_bounds__(256) void k_crfc(const float* __restrict__ trans, char* __restrict__ ws)
{
    __shared__ float trL[16 * 17];
    __shared__ float est[16 * 16];
    __shared__ float Pb[2][16 * 17];
    int blk = blockIdx.x, tid = threadIdx.x;
    int b = blk >> 5, c = blk & 31;
    int t = tid >> 4, p = tid & 15;
    const float* emis = (const float*)(ws + WS_EMIS);
    float* chk = (float*)(ws + WS_CHK);
    trL[t * 17 + p] = trans[t * 16 + p];
    est[t * 16 + p] = emis[((size_t)b * 512 + c * 16 + t) * 16 + p];
    __syncthreads();
    float tr[16];
    #pragma unroll
    for (int q = 0; q < 16; ++q) tr[q] = trL[t * 17 + q];
    float out = trL[t * 17 + p] + est[0 * 16 + t];
    Pb[0][t * 17 + p] = out;
    __syncthreads();
    int cur = 0;
    for (int si = 1; si < 16; ++si) {
        float v[16]; float mx = -3.0e38f;
        #pragma unroll
        for (int q = 0; q < 16; ++q) { v[q] = tr[q] + Pb[cur][q * 17 + p]; mx = fmaxf(mx, v[q]); }
        float ss = 0.f;
        #pragma unroll
        for (int q = 0; q < 16; ++q) ss += __expf(v[q] - mx);
        out = est[si * 16 + t] + mx + __logf(ss);
        Pb[1 - cur][t * 17 + p] = out;
        __syncthreads();
        cur = 1 - cur;
    }
    chk[(size_t)(b * 32 + c) * 256 + t * 16 + p] = out;
}

// ============ kernel 6: fold 32 chunk matrices per batch, apply alpha0/stop, emit log_Z ============
__global__ __launch_bounds__(256) void k_crff(
    const float* __restrict__ trans, char* __restrict__ ws, float* __restrict__ out)
{
    __shared__ float Cst[16 * 17];
    __shared__ float Pb[2][16 * 17];
    __shared__ float af[16];
    int b = blockIdx.x, tid = threadIdx.x;
    int t = tid >> 4, p = tid & 15;
    const float* chk = (const float*)(ws + WS_CHK);
    Pb[0][t * 17 + p] = chk[(size_t)(b * 32) * 256 + t * 16 + p];
    __syncthreads();
    int cur = 0;
    for (int ci = 1; ci < 32; ++ci) {
        Cst[t * 17 + p] = chk[(size_t)(b * 32 + ci) * 256 + t * 16 + p];
        __syncthreads();
        float v[16]; float mx = -3.0e38f;
        #pragma unroll
        for (int q = 0; q < 16; ++q) { v[q] = Cst[t * 17 + q] + Pb[cur][q * 17 + p]; mx = fmaxf(mx, v[q]); }
        float ss = 0.f;
        #pragma unroll
        for (int q = 0; q < 16; ++q) ss += __expf(v[q] - mx);
        float outv = mx + __logf(ss);
        Pb[1 - cur][t * 17 + p] = outv;
        __syncthreads();
        cur = 1 - cur;
    }
    float vfin = Pb[cur][t * 17 + p] + ((p == 14) ? 0.0f : -10000.0f);  // alpha0: START=14
    Cst[t * 17 + p] = vfin;
    __syncthreads();
    if (tid < 16) {
        float mx = -3.0e38f;
        for (int q = 0; q < 16; ++q) mx = fmaxf(mx, Cst[tid * 17 + q]);
        float ss = 0.f;
        for (int q = 0; q < 16; ++q) ss += __expf(Cst[tid * 17 + q] - mx);
        af[tid] = mx + __logf(ss) + trans[15 * 16 + tid];               // STOP=15
    }
    __syncthreads();
    if (tid == 0) {
        float mx = -3.0e38f;
        for (int q = 0; q < 16; ++q) mx = fmaxf(mx, af[q]);
        float ss = 0.f;
        for (int q = 0; q < 16; ++q) ss += __expf(af[q] - mx);
        out[b] = mx + __logf(ss);
    }
}

extern "C" void kernel_launch(void* const* d_in, const int* in_sizes, int n_in,
                              void* d_out, int out_size, void* d_ws, size_t ws_size,
                              hipStream_t stream)
{
    const int*   tokens = (const int*)d_in[0];
    const float* embed  = (const float*)d_in[1];
    const float* Wi_f   = (const float*)d_in[2];
    const float* Wh_f   = (const float*)d_in[3];
    const float* bi_f   = (const float*)d_in[4];
    const float* bh_f   = (const float*)d_in[5];
    const float* Wi_b   = (const float*)d_in[6];
    const float* Wh_b   = (const float*)d_in[7];
    const float* bi_b   = (const float*)d_in[8];
    const float* bh_b   = (const float*)d_in[9];
    const float* Wt     = (const float*)d_in[10];
    const float* bt     = (const float*)d_in[11];
    const float* trans  = (const float*)d_in[12];
    char* ws = (char*)d_ws;
    float* out = (float*)d_out;

    hipLaunchKernelGGL(k_prep, dim3(2560), dim3(256), 0, stream,
                       tokens, embed, Wi_f, Wi_b, bi_f, bh_f, bi_b, bh_b, ws);
    hipLaunchKernelGGL(k_pregemm, dim3(4096), dim3(256), 0, stream, ws);
    hipLaunchKernelGGL(k_rec, dim3(8), dim3(512), 0, stream, Wh_f, Wh_b, ws);
    hipLaunchKernelGGL(k_emis, dim3(1024), dim3(256), 0, stream, Wt, bt, ws);
    hipLaunchKernelGGL(k_crfc, dim3(1024), dim3(256), 0, stream, trans, ws);
    hipLaunchKernelGGL(k_crff, dim3(32), dim3(256), 0, stream, trans, ws, out);
}